// Round 6
// baseline (349.008 us; speedup 1.0000x reference)
//
#include <hip/hip_runtime.h>
#include <hip/hip_bf16.h>

#define LO 506      // L_out
#define LL 512      // L
#define CC 128      // C
#define FF 128      // F
#define KC 896      // K*C (reduction dim)
#define BK 32       // K-tile
#define NK 28       // 896/32 (divisible by 4: clean 4-deep W rotation)
#define XS 40       // Xs row stride in bf16 (32 + 8 pad; 80 B rows: 16B-aligned b128, 2-way banks = free)
#define WS 40       // Wt row stride in bf16

typedef __attribute__((ext_vector_type(8))) short short8;     // 8 bf16 = 4 VGPR (MFMA operand)
typedef __attribute__((ext_vector_type(4))) float floatx4;    // MFMA acc / float4 load
typedef __attribute__((ext_vector_type(4))) unsigned int uintx4;
typedef unsigned short ushort_t;

// Native RNE f32->bf16 (backend fuses pairs into v_cvt_pk_bf16_f32)
static __device__ __forceinline__ unsigned int pk2(float a, float b) {
    __hip_bfloat16 ha = __float2bfloat16(a);
    __hip_bfloat16 hb = __float2bfloat16(b);
    unsigned short ua, ub;
    __builtin_memcpy(&ua, &ha, 2);
    __builtin_memcpy(&ub, &hb, 2);
    return (unsigned int)ua | ((unsigned int)ub << 16);
}

// grid = 506, one block per l, 512 threads = 8 waves, full 128b x 128f tile.
// Base = R3/R5 champion (347 us): XCD-chunk swizzle, LDS double-buffer,
// LDS-only-drain barriers (global loads stay in flight), nt W loads/out stores.
// This round: W prefetch deepened 2 -> 4 tiles (A stays 2-deep; x is L2/L3-
// resident, only the HBM-latency W stream needs depth). Keeps the VMEM pipe
// issuing across the whole iteration instead of two bursts -> sustain the
// ~10 B/cy/CU HBM share. VGPR ~116 < 128 cap (launch_bounds 512,4).
__global__ __launch_bounds__(512, 4)
void local_block_kernel(const float* __restrict__ x,
                        const float* __restrict__ wg,
                        const float* __restrict__ bias,
                        const float* __restrict__ gamma,
                        const float* __restrict__ beta,
                        const float* __restrict__ mmean,
                        const float* __restrict__ mvar,
                        float* __restrict__ out)
{
    // ---- bijective XCD-chunk swizzle (nwg=506, 8 XCDs: chunks 64,64,63x6)
    const int bid = blockIdx.x;
    const int xcd = bid & 7;
    const int idx = bid >> 3;
    const int q8  = LO >> 3;              // 63
    const int r8  = LO & 7;               // 2
    const int l   = (xcd < r8) ? xcd * (q8 + 1) + idx
                               : r8 * (q8 + 1) + (xcd - r8) * q8 + idx;

    const int t    = threadIdx.x;         // 512 threads = 8 waves
    const int lane = t & 63;
    const int wave = t >> 6;              // 0..7
    const int q    = lane >> 4;           // quad within wave (k-group)
    const int l16  = lane & 15;
    const int wr   = wave >> 1;           // wave row: batch 32-block (0..3)
    const int wc   = wave & 1;            // wave col: f 64-half

    __shared__ __align__(16) ushort_t Xs[2][128 * XS];   // 2 x 10 KB
    __shared__ __align__(16) ushort_t Wt[2][128 * WS];   // 2 x 10 KB  (40 KB total)

    // ---- A staging map: thread -> (row = t>>2, k-chunk = (t&3)*8); 8 floats = 2 float4
    const int am  = t >> 2;
    const int ak0 = (t & 3) * 8;
    const float* aptr = x + (size_t)am * (LL * CC) + l * CC + ak0;

    // ---- W staging map: thread -> (f = t&127, k 8-group = (t>>7)*8); 8 strided dword loads
    const int wf  = t & 127;
    const int wk  = (t >> 7) * 8;         // 0,8,16,24
    const float* wptr = wg + (size_t)l * (KC * FF) + wf;

    floatx4 acc[2][4] = {};               // 32 fp32 accumulators

    floatx4 areg0[2], areg1[2];           // 2-deep A prefetch (16 VGPR)
    float   wregA[8], wregB[8], wregC[8], wregD[8];   // 4-deep W prefetch (32 VGPR)

#define LOAD_A(AR, KT) { const float* p = aptr + (KT) * BK;                     \
        AR[0] = *(const floatx4*)(p);                                           \
        AR[1] = *(const floatx4*)(p + 4); }

#define LOAD_W(WR, KT) { const float* p = wptr + (size_t)((KT) * BK + wk) * FF; \
        _Pragma("unroll") for (int j = 0; j < 8; ++j)                           \
            WR[j] = __builtin_nontemporal_load(p + j * FF); }

#define STAGE(S, AR, WR) {                                                      \
        uintx4 av = { pk2(AR[0].x, AR[0].y), pk2(AR[0].z, AR[0].w),             \
                      pk2(AR[1].x, AR[1].y), pk2(AR[1].z, AR[1].w) };           \
        *(uintx4*)&Xs[S][am * XS + ak0] = av;                                   \
        uintx4 wv = { pk2(WR[0], WR[1]), pk2(WR[2], WR[3]),                     \
                      pk2(WR[4], WR[5]), pk2(WR[6], WR[7]) };                   \
        *(uintx4*)&Wt[S][wf * WS + wk] = wv; }

    // LDS-only drain barrier: prefetch global loads stay in flight (no vmcnt)
#define BAR() {                                                                 \
        asm volatile("s_waitcnt lgkmcnt(0)" ::: "memory");                      \
        __builtin_amdgcn_s_barrier();                                           \
        asm volatile("" ::: "memory"); }

#define COMPUTE(S) {                                                            \
        short8 af[2], bfr[4];                                                   \
        _Pragma("unroll") for (int mi = 0; mi < 2; ++mi)                        \
            af[mi] = *(const short8*)&Xs[S][(wr*32 + mi*16 + l16) * XS + q*8];  \
        _Pragma("unroll") for (int ni = 0; ni < 4; ++ni)                        \
            bfr[ni] = *(const short8*)&Wt[S][(wc*64 + ni*16 + l16) * WS + q*8]; \
        _Pragma("unroll") for (int mi = 0; mi < 2; ++mi)                        \
            _Pragma("unroll") for (int ni = 0; ni < 4; ++ni)                    \
                acc[mi][ni] = __builtin_amdgcn_mfma_f32_16x16x32_bf16(          \
                    af[mi], bfr[ni], acc[mi][ni], 0, 0, 0); }

    // one tile: stage oldest regs, refill (A 2-ahead, W 4-ahead), barrier, MFMA
#define TILE(S, AR, WR, KT) {                                                   \
        STAGE(S, AR, WR);                                                       \
        if ((KT) + 2 < NK) LOAD_A(AR, (KT) + 2);                                \
        if ((KT) + 4 < NK) LOAD_W(WR, (KT) + 4);                                \
        BAR();                                                                  \
        COMPUTE(S); }

    LOAD_A(areg0, 0); LOAD_W(wregA, 0);
    LOAD_A(areg1, 1); LOAD_W(wregB, 1);
    LOAD_W(wregC, 2); LOAD_W(wregD, 3);

    for (int base = 0; base < NK; base += 4) {
        TILE(0, areg0, wregA, base + 0);
        TILE(1, areg1, wregB, base + 1);
        TILE(0, areg0, wregC, base + 2);
        TILE(1, areg1, wregD, base + 3);
    }

    // ---- epilogue: fold bias + BN into per-f scale/offset, relu, nontemporal store
#pragma unroll
    for (int ni = 0; ni < 4; ++ni) {
        int f = wc*64 + ni*16 + l16;
        float inv = gamma[f] * rsqrtf(mvar[f] + 1e-3f);
        float off = bias[l * FF + f] * inv + beta[f] - mmean[f] * inv;
#pragma unroll
        for (int mi = 0; mi < 2; ++mi) {
#pragma unroll
            for (int rg = 0; rg < 4; ++rg) {
                int b = wr*32 + mi*16 + q*4 + rg;   // C/D: row=(lane>>4)*4+reg
                float v = acc[mi][ni][rg] * inv + off;
                __builtin_nontemporal_store(fmaxf(v, 0.0f),
                    &out[((size_t)b * LO + l) * FF + f]);
            }
        }
    }
#undef LOAD_A
#undef LOAD_W
#undef STAGE
#undef BAR
#undef COMPUTE
#undef TILE
}

extern "C" void kernel_launch(void* const* d_in, const int* in_sizes, int n_in,
                              void* d_out, int out_size, void* d_ws, size_t ws_size,
                              hipStream_t stream) {
    const float* x     = (const float*)d_in[0];
    const float* w     = (const float*)d_in[1];
    const float* bias  = (const float*)d_in[2];
    const float* gamma = (const float*)d_in[3];
    const float* beta  = (const float*)d_in[4];
    const float* mmean = (const float*)d_in[5];
    const float* mvar  = (const float*)d_in[6];
    float* out = (float*)d_out;

    local_block_kernel<<<dim3(LO), dim3(512), 0, stream>>>(
        x, w, bias, gamma, beta, mmean, mvar, out);
}